// Round 1
// 447.805 us; speedup vs baseline: 1.0139x; 1.0139x over previous
//
#include <hip/hip_runtime.h>
#include <stdint.h>

#define DEVI __device__ __forceinline__

typedef __bf16 bf16x8 __attribute__((ext_vector_type(8)));
typedef float  floatx4 __attribute__((ext_vector_type(4)));

// B=8, S=2048, H=1024. M = B*S = 16384.
// ws: Q @0 (32MiB, pre-scaled 1/32) | K @+32M | Vt @+64M ([8][1024 d][2048 k])
//     lvec @+96M (f32[16384]) | P @+96M+64K (bf16 [8][2048][2048]);
//     P region overlays Xb (32MiB) + Wt (6MiB), dead before P written.
//
// Round-5: k_gemm ported from 128^2 2-barrier (m97-class, ~900TF ceiling,
// measured 500-665TF here) to 256^2 8-wave 4-phase/K-tile counted-vmcnt
// schedule (T2+T3+T4+T5). Schedule invariants (DO NOT edit stages/waits
// without re-deriving):
//   tile t lives in buf[t&1]; phases of tile t: p1=(MH0,NH0) p2=(MH0,NH1)
//   p3=(MH1,NH0) p4=(MH1,NH1).
//   AH0 = A rows {0-63,128-191} (read p1,p2)   AH1 = +64 (read p3,p4)
//   BH0 = B rows {g*64+[0,32)}  (read p1,p3)   BH1 = +32 (read p2,p4)
//   stage AH1(t+1)@p1, BH1(t+1)@p2 (into buf[t&1^1], dead since end of t-1)
//   stage AH0(t+2)@p3, BH0(t+2)@p4 (into buf[t&1], region dead 1 phase ago)
//   s_waitcnt vmcnt(4) at p4 only (2 newest stage-pairs may stay in flight)
//   -> tile t+1's 4 halves are guaranteed landed; tails drop to vmcnt(0).
// (Round-2..4 notes kept: do NOT replace with 32x32 MFMA, LDS-staged
// epilogue, or B-direct loads — all measured regressions.)

DEVI unsigned short f2bf(float f) {
  union { float f; uint32_t u; } x; x.f = f;
  return (unsigned short)((x.u + 0x7fffu + ((x.u >> 16) & 1u)) >> 16);
}
DEVI float bf2f(unsigned short s) {
  union { uint32_t u; float f; } x; x.u = ((uint32_t)s) << 16;
  return x.f;
}

// ---------------- fused prep: X->bf16, 3x W transpose->bf16, lvec=0 ----------------
__global__ __launch_bounds__(256) void k_prep(
    const float* __restrict__ X, unsigned short* __restrict__ Xb,
    const float* __restrict__ Wq, const float* __restrict__ Wk,
    const float* __restrict__ Wv, unsigned short* __restrict__ Wt,
    float* __restrict__ lvec) {
  __shared__ float tile[64][65];
  int bx = blockIdx.x, t = threadIdx.x;
  if (bx < 16384) {                 // convert X: 4194304 float4 groups
    int i = bx * 256 + t;
    float4 v = ((const float4*)X)[i];
    ushort4 o;
    o.x = f2bf(v.x); o.y = f2bf(v.y); o.z = f2bf(v.z); o.w = f2bf(v.w);
    ((ushort4*)Xb)[i] = o;
  } else if (bx < 17152) {          // 3 x 256 transpose blocks
    int idx = bx - 16384;
    int sel = idx >> 8, b2 = idx & 255;
    const float* W = sel == 0 ? Wq : (sel == 1 ? Wk : Wv);
    unsigned short* Wo = Wt + ((size_t)sel << 20);
    int h0 = (b2 & 15) * 64, d0 = (b2 >> 4) * 64;
#pragma unroll
    for (int i = 0; i < 16; ++i) {
      int idx2 = i * 256 + t; int r = idx2 >> 6, c = idx2 & 63;
      tile[r][c] = W[(size_t)(h0 + r) * 1024 + d0 + c];
    }
    __syncthreads();
#pragma unroll
    for (int i = 0; i < 16; ++i) {
      int idx2 = i * 256 + t; int r = idx2 >> 6, c = idx2 & 63;
      Wo[(size_t)(d0 + r) * 1024 + h0 + c] = f2bf(tile[c][r]);
    }
  } else {                          // zero lvec (16384 f32)
    float4 z4 = {0.f, 0.f, 0.f, 0.f};
#pragma unroll
    for (int i = 0; i < 16; ++i) ((float4*)lvec)[i * 256 + t] = z4;
  }
}

// ---------------- async 16B global -> LDS ----------------
DEVI void gl_lds16(const unsigned short* gp, unsigned short* lp) {
  __builtin_amdgcn_global_load_lds(
      (const __attribute__((address_space(1))) void*)gp,
      (__attribute__((address_space(3))) void*)lp, 16, 0, 0);
}

// Stage one half-tile (128 rows x 64 cols bf16 = 16KiB) with 16B-unit XOR
// swizzle: LDS(r, cu) = G(r, cu ^ (r&7)). Linear LDS dest (wave-uniform base
// + lane*16), pre-swizzled per-lane global source. 2 gl_lds16 per thread.
// A halves (q): rows blk*128 + q*64 + [0,64).  B halves: rows grp*64 + q*32 + [0,32).
template <bool ISB>
DEVI void stage_half(const unsigned short* __restrict__ G, unsigned short* L,
                     int base, int ld, int kt, int q, int w, int l) {
#pragma unroll
  for (int j = 0; j < 2; ++j) {
    int slot = w * 2 + j;
    int r0 = ISB ? ((slot >> 2) * 64 + q * 32 + (slot & 3) * 8)
                 : ((slot >> 3) * 128 + q * 64 + (slot & 7) * 8);
    int r = r0 + (l >> 3);
    int u = (l & 7) ^ (r & 7);
    gl_lds16(G + (size_t)(base + r) * ld + (size_t)kt * 64 + u * 8, L + r0 * 64);
  }
}

// One phase: frag ds-reads, one half-tile stage, barrier, MFMA quadrant,
// optional counted vmcnt, barrier. Compiler inserts counted lgkmcnt between
// ds_read and MFMA (m97 evidence: near-optimal); vmcnt is manual since the
// gl_lds16 -> ds_read RAW is invisible to it.
#define PHASE(MH, NH, WAITSTMT, ...)                                          \
  do {                                                                        \
    bf16x8 af[2][4], bfr[2][2];                                               \
    _Pragma("unroll") for (int kk = 0; kk < 2; ++kk) {                        \
      _Pragma("unroll") for (int ms = 0; ms < 4; ++ms) {                      \
        int rr = wm + MH * 64 + ms * 16 + l15;                                \
        int cc = (kk * 4 + quad) ^ (rr & 7);                                  \
        af[kk][ms] = *(const bf16x8*)&Ac[rr * 64 + cc * 8];                   \
      }                                                                       \
      _Pragma("unroll") for (int ns = 0; ns < 2; ++ns) {                      \
        int rr = wn + NH * 32 + ns * 16 + l15;                                \
        int cc = (kk * 4 + quad) ^ (rr & 7);                                  \
        bfr[kk][ns] = *(const bf16x8*)&Bc[rr * 64 + cc * 8];                  \
      }                                                                       \
    }                                                                         \
    __VA_ARGS__;                                                              \
    __builtin_amdgcn_s_barrier();                                             \
    __builtin_amdgcn_s_setprio(1);                                            \
    _Pragma("unroll") for (int kk = 0; kk < 2; ++kk)                          \
      _Pragma("unroll") for (int ms = 0; ms < 4; ++ms)                        \
        _Pragma("unroll") for (int ns = 0; ns < 2; ++ns)                      \
          acc[MH * 4 + ms][NH * 2 + ns] =                                     \
              __builtin_amdgcn_mfma_f32_16x16x32_bf16(                        \
                  af[kk][ms], bfr[kk][ns], acc[MH * 4 + ms][NH * 2 + ns],     \
                  0, 0, 0);                                                   \
    __builtin_amdgcn_s_setprio(0);                                            \
    WAITSTMT;                                                                 \
    __builtin_amdgcn_s_barrier();                                             \
  } while (0)

#define WAITV4 asm volatile("s_waitcnt vmcnt(4)" ::: "memory")
#define WAITV0 asm volatile("s_waitcnt vmcnt(0)" ::: "memory")

// ---------------- C = A * Bt^T  (both bf16 row-major, K-major rows) ----------------
// 256x256 tile, BK=64, 8 waves (2M x 4N, 128x64 each), 128KiB dbuf LDS.
// EPI: 4 = fused QKV (sel=blockIdx.y>>2): Q (x+b)/32, K x+b, V -> Vt[b][d][k]
//      2 = P = exp(S) masked, bf16; atomic row sums -> lsum
//      3 = O = (P*V) * 1/lvec[row], f32
template <int EPI>
__global__ __launch_bounds__(512, 2) void k_gemm(
    const unsigned short* __restrict__ A, const unsigned short* __restrict__ Bt,
    void* __restrict__ Cv,
    const float* __restrict__ bias_q, const float* __restrict__ bias_k,
    const float* __restrict__ bias_v,
    const float* __restrict__ lvec, float* __restrict__ lsum,
    const int* __restrict__ mask,
    long aZ, long bZ, int ldA, int ldB, int kIters)
{
  __shared__ __attribute__((aligned(16))) unsigned short As[2][256 * 64];
  __shared__ __attribute__((aligned(16))) unsigned short Bs[2][256 * 64];
  const int tid = threadIdx.x, w = tid >> 6, l = tid & 63;
  const int quad = l >> 4, l15 = l & 15;
  const int wr = w & 1, wc = w >> 1;           // 2M x 4N wave grid
  const int wm = wr * 128, wn = wc * 64;
  const int m0 = blockIdx.x * 256;
  const int z = blockIdx.z;

  int n0, sel = 0;
  if constexpr (EPI == 4) { sel = blockIdx.y >> 2; n0 = (blockIdx.y & 3) * 256; }
  else n0 = blockIdx.y * 256;

  const unsigned short* Az = A + (size_t)z * aZ;
  const unsigned short* Bz = (EPI == 4) ? (Bt + ((size_t)sel << 20))
                                        : (Bt + (size_t)z * bZ);

  floatx4 acc[8][4];
#pragma unroll
  for (int i = 0; i < 8; ++i)
#pragma unroll
    for (int j = 0; j < 4; ++j) { floatx4 zz = {0.f, 0.f, 0.f, 0.f}; acc[i][j] = zz; }

  // -------- prologue: tile0 full + AH0/BH0(1); tile0 guaranteed landed --------
  stage_half<false>(Az, As[0], m0, ldA, 0, 0, w, l);   // AH0(0)
  stage_half<true >(Bz, Bs[0], n0, ldB, 0, 0, w, l);   // BH0(0)
  stage_half<false>(Az, As[0], m0, ldA, 0, 1, w, l);   // AH1(0)
  stage_half<true >(Bz, Bs[0], n0, ldB, 0, 1, w, l);   // BH1(0)
  if (kIters > 1) {
    stage_half<false>(Az, As[1], m0, ldA, 1, 0, w, l); // AH0(1)
    stage_half<true >(Bz, Bs[1], n0, ldB, 1, 0, w, l); // BH0(1)
    WAITV4;
  } else {
    WAITV0;
  }
  __builtin_amdgcn_s_barrier();

  // -------- main loop: 4 phases per K-tile, counted vmcnt at p4 only --------
#pragma unroll 2
  for (int kt = 0; kt < kIters; ++kt) {
    const int bc = kt & 1, bn = bc ^ 1;
    const unsigned short* Ac = As[bc];
    const unsigned short* Bc = Bs[bc];
    PHASE(0, 0, {},
          if (kt + 1 < kIters) stage_half<false>(Az, As[bn], m0, ldA, kt + 1, 1, w, l));
    PHASE(0, 1, {},
          if (kt + 1 < kIters) stage_half<true >(Bz, Bs[bn], n0, ldB, kt + 1, 1, w, l));
    PHASE(1, 0, {},
          if (kt + 2 < kIters) stage_half<false>(Az, As[bc], m0, ldA, kt + 2, 0, w, l));
    PHASE(1, 1,
          { if (kt + 2 < kIters) { WAITV4; } else { WAITV0; } },
          if (kt + 2 < kIters) stage_half<true >(Bz, Bs[bc], n0, ldB, kt + 2, 0, w, l));
  }

  // epilogue: C/D layout col = lane&15, row = quad*4 + reg  [m89/m91]
  if constexpr (EPI == 4) {
    unsigned short* C = (unsigned short*)Cv + ((size_t)sel << 24);
    const float* bs = sel == 0 ? bias_q : (sel == 1 ? bias_k : bias_v);
    if (sel < 2) {
      float sc = sel == 0 ? 0.03125f : 1.0f;
#pragma unroll
      for (int ns = 0; ns < 4; ++ns) {
        int n_g = n0 + wn + ns * 16 + l15;
        float bv = bs[n_g];
#pragma unroll
        for (int ms = 0; ms < 8; ++ms) {
          int mb = m0 + wm + ms * 16 + quad * 4;
#pragma unroll
          for (int r = 0; r < 4; ++r)
            C[(size_t)(mb + r) * 1024 + n_g] = f2bf((acc[ms][ns][r] + bv) * sc);
        }
      }
    } else {
      // V -> Vt[b][d][k]: the 4 r-values are CONSECUTIVE in k -> pack 8B stores
#pragma unroll
      for (int ns = 0; ns < 4; ++ns) {
        int n_g = n0 + wn + ns * 16 + l15;
        float bv = bs[n_g];
#pragma unroll
        for (int ms = 0; ms < 8; ++ms) {
          int m_g = m0 + wm + ms * 16 + quad * 4;   // r=0 element
          int bb = m_g >> 11, key = m_g & 2047;
          ushort4 pk;
          pk.x = f2bf(acc[ms][ns][0] + bv);
          pk.y = f2bf(acc[ms][ns][1] + bv);
          pk.z = f2bf(acc[ms][ns][2] + bv);
          pk.w = f2bf(acc[ms][ns][3] + bv);
          *(ushort4*)&C[((size_t)bb << 21) + ((size_t)n_g << 11) + key] = pk;
        }
      }
    }
  } else if constexpr (EPI == 2) {
    // P = exp(S) (max-free: |S| <= ~6), masked; atomic rowsums
    unsigned short* C = (unsigned short*)Cv + (size_t)z * 4194304;
    const int* mz = mask + z * 2048;
    float rowsum[8][4];
#pragma unroll
    for (int ms = 0; ms < 8; ++ms)
#pragma unroll
      for (int r = 0; r < 4; ++r) rowsum[ms][r] = 0.f;
#pragma unroll
    for (int ns = 0; ns < 4; ++ns) {
      int n_g = n0 + wn + ns * 16 + l15;
      int mv = mz[n_g];
#pragma unroll
      for (int ms = 0; ms < 8; ++ms) {
#pragma unroll
        for (int r = 0; r < 4; ++r) {
          int m_g = m0 + wm + ms * 16 + quad * 4 + r;
          float e = mv ? __expf(acc[ms][ns][r]) : 0.f;
          unsigned short pb = f2bf(e);
          C[(size_t)m_g * 2048 + n_g] = pb;
          rowsum[ms][r] += bf2f(pb);
        }
      }
    }
#pragma unroll
    for (int ms = 0; ms < 8; ++ms) {
#pragma unroll
      for (int r = 0; r < 4; ++r) {
        float s = rowsum[ms][r];
#pragma unroll
        for (int off = 1; off < 16; off <<= 1) s += __shfl_xor(s, off);
        if (l15 == 0) {
          int m_g = m0 + wm + ms * 16 + quad * 4 + r;
          atomicAdd(&lsum[z * 2048 + m_g], s);
        }
      }
    }
  } else {  // EPI == 3: O = (P*V)/l
    float* C = (float*)Cv + (size_t)z * 2048 * 1024;
    const float* lz = lvec + z * 2048;
#pragma unroll
    for (int ms = 0; ms < 8; ++ms) {
#pragma unroll
      for (int r = 0; r < 4; ++r) {
        int m_g = m0 + wm + ms * 16 + quad * 4 + r;
        float lw = lz[m_g];
        float inv = lw > 0.f ? 1.f / lw : 0.f;
#pragma unroll
        for (int ns = 0; ns < 4; ++ns) {
          int n_g = n0 + wn + ns * 16 + l15;
          C[(size_t)m_g * 1024 + n_g] = acc[ms][ns][r] * inv;
        }
      }
    }
  }
}

extern "C" void kernel_launch(void* const* d_in, const int* in_sizes, int n_in,
                              void* d_out, int out_size, void* d_ws, size_t ws_size,
                              hipStream_t stream) {
  const float* X    = (const float*)d_in[0];
  const int*   mask = (const int*)d_in[1];
  const float* Wq   = (const float*)d_in[2];
  const float* bq   = (const float*)d_in[3];
  const float* Wk   = (const float*)d_in[4];
  const float* bk   = (const float*)d_in[5];
  const float* Wv   = (const float*)d_in[6];
  const float* bv   = (const float*)d_in[7];
  float* out = (float*)d_out;

  constexpr size_t SZ = (size_t)16384 * 1024;
  unsigned short* Q    = (unsigned short*)d_ws;      // Q|K|Vt contiguous (sel<<24)
  float*          lvec = (float*)(Q + 3 * SZ);
  unsigned short* P    = (unsigned short*)(lvec + 16384);
  unsigned short* Xb   = P;               // overlaid: dead before P written
  unsigned short* Wt   = Xb + SZ;         // 3 x [1024][1024] bf16
  unsigned short* Vt   = Q + 2 * SZ;

  // 1. prep: X->bf16, W->Wt (bf16, transposed), lvec=0
  k_prep<<<dim3(17153), 256, 0, stream>>>(X, Xb, Wq, Wk, Wv, Wt, lvec);

  // 2. fused QKV projection (12 n-strips: 4 Q, 4 K, 4 V)
  k_gemm<4><<<dim3(64, 12, 1), 512, 0, stream>>>(
      Xb, Wt, (void*)Q, bq, bk, bv, nullptr, nullptr, nullptr,
      0, 0, 1024, 1024, 16);

  // 3. P = exp(Q K^T) masked + atomic row sums
  k_gemm<2><<<dim3(8, 8, 8), 512, 0, stream>>>(
      Q, Q + SZ, (void*)P, nullptr, nullptr, nullptr, nullptr, lvec, mask,
      2048 * 1024, 2048 * 1024, 1024, 1024, 16);

  // 4. O = (P V) / l  -> fp32 out
  k_gemm<3><<<dim3(8, 4, 8), 512, 0, stream>>>(
      P, Vt, (void*)out, nullptr, nullptr, nullptr, lvec, nullptr, nullptr,
      2048 * 2048, 1024 * 2048, 2048, 2048, 32);
}

// Round 2
// 408.070 us; speedup vs baseline: 1.1126x; 1.0974x over previous
//
#include <hip/hip_runtime.h>
#include <stdint.h>

#define DEVI __device__ __forceinline__

typedef __bf16 bf16x8 __attribute__((ext_vector_type(8)));
typedef float  floatx4 __attribute__((ext_vector_type(4)));

// B=8, S=2048, H=1024. M = B*S = 16384.
// ws: Q @0 (32MiB, pre-scaled 1/32) | K @+32M | Vt @+64M ([8][1024 d][2048 k])
//     lvec @+96M (f32[16384]) | P @+96M+64K (bf16 [8][2048][2048]);
//     P region overlays Xb (32MiB) + Wt (6MiB), dead before P written.
//
// Round-6: round-5's 4-phase schedule was LDS-read-BW-bound (96KB/CU/phase,
// MfmaUtil 28%, ~1900cy/phase vs 515cy MFMA). This round: register fragment
// reuse + phase order (0,0),(0,1),(1,1),(1,0). Per-tile ds_reads 48 -> 24
// (the unique minimum): p1=12 (A0+B0), p2=4 (B1), p3=8 (A1), p4=0.
//   af   held p1-p2 (MH0) then reloaded p3 for p3-p4 (MH1)
//   bfr0 (NH0) held p1..p4;  bfr1 (NH1) held p2..p3
// Stage/wait schedule UNCHANGED from round-5 (re-derived):
//   LDS-region last-read map per tile t: AH0@p1, BH0@p1, BH1@p2, AH1@p3, p4 none.
//   stage AH1(t+1)@p1, BH1(t+1)@p2 into bn (regions last read in tile t-1) OK
//   stage AH0(t+2)@p3 into bc-AH0 (last read p1, 2 barriers earlier) OK
//   stage BH0(t+2)@p4 into bc-BH0 (last read p1; p4 reads NOTHING now) OK
//   vmcnt(4)@p4 retires all 4 halves of tile t+1, leaves {AH0,BH0}(t+2) in
//   flight; tails drop to vmcnt(0).
// (Kept: do NOT replace with 32x32 MFMA, LDS-staged epilogue, or B-direct
// loads — all measured regressions in earlier rounds.)

DEVI unsigned short f2bf(float f) {
  union { float f; uint32_t u; } x; x.f = f;
  return (unsigned short)((x.u + 0x7fffu + ((x.u >> 16) & 1u)) >> 16);
}
DEVI float bf2f(unsigned short s) {
  union { uint32_t u; float f; } x; x.u = ((uint32_t)s) << 16;
  return x.f;
}

// ---------------- fused prep: X->bf16, 3x W transpose->bf16, lvec=0 ----------------
__global__ __launch_bounds__(256) void k_prep(
    const float* __restrict__ X, unsigned short* __restrict__ Xb,
    const float* __restrict__ Wq, const float* __restrict__ Wk,
    const float* __restrict__ Wv, unsigned short* __restrict__ Wt,
    float* __restrict__ lvec) {
  __shared__ float tile[64][65];
  int bx = blockIdx.x, t = threadIdx.x;
  if (bx < 16384) {                 // convert X: 4194304 float4 groups
    int i = bx * 256 + t;
    float4 v = ((const float4*)X)[i];
    ushort4 o;
    o.x = f2bf(v.x); o.y = f2bf(v.y); o.z = f2bf(v.z); o.w = f2bf(v.w);
    ((ushort4*)Xb)[i] = o;
  } else if (bx < 17152) {          // 3 x 256 transpose blocks
    int idx = bx - 16384;
    int sel = idx >> 8, b2 = idx & 255;
    const float* W = sel == 0 ? Wq : (sel == 1 ? Wk : Wv);
    unsigned short* Wo = Wt + ((size_t)sel << 20);
    int h0 = (b2 & 15) * 64, d0 = (b2 >> 4) * 64;
#pragma unroll
    for (int i = 0; i < 16; ++i) {
      int idx2 = i * 256 + t; int r = idx2 >> 6, c = idx2 & 63;
      tile[r][c] = W[(size_t)(h0 + r) * 1024 + d0 + c];
    }
    __syncthreads();
#pragma unroll
    for (int i = 0; i < 16; ++i) {
      int idx2 = i * 256 + t; int r = idx2 >> 6, c = idx2 & 63;
      Wo[(size_t)(d0 + r) * 1024 + h0 + c] = f2bf(tile[c][r]);
    }
  } else {                          // zero lvec (16384 f32)
    float4 z4 = {0.f, 0.f, 0.f, 0.f};
#pragma unroll
    for (int i = 0; i < 16; ++i) ((float4*)lvec)[i * 256 + t] = z4;
  }
}

// ---------------- async 16B global -> LDS ----------------
DEVI void gl_lds16(const unsigned short* gp, unsigned short* lp) {
  __builtin_amdgcn_global_load_lds(
      (const __attribute__((address_space(1))) void*)gp,
      (__attribute__((address_space(3))) void*)lp, 16, 0, 0);
}

// Stage one half-tile (128 rows x 64 cols bf16 = 16KiB) with 16B-unit XOR
// swizzle: LDS(r, cu) = G(r, cu ^ (r&7)). Linear LDS dest (wave-uniform base
// + lane*16), pre-swizzled per-lane global source. 2 gl_lds16 per thread.
// A halves (q): rows blk*128 + q*64 + [0,64).  B halves: rows grp*64 + q*32 + [0,32).
template <bool ISB>
DEVI void stage_half(const unsigned short* __restrict__ G, unsigned short* L,
                     int base, int ld, int kt, int q, int w, int l) {
#pragma unroll
  for (int j = 0; j < 2; ++j) {
    int slot = w * 2 + j;
    int r0 = ISB ? ((slot >> 2) * 64 + q * 32 + (slot & 3) * 8)
                 : ((slot >> 3) * 128 + q * 64 + (slot & 7) * 8);
    int r = r0 + (l >> 3);
    int u = (l & 7) ^ (r & 7);
    gl_lds16(G + (size_t)(base + r) * ld + (size_t)kt * 64 + u * 8, L + r0 * 64);
  }
}

// Fragment loads (XOR-swizzled). rr&7 == l15&7 (all other terms mult of 8).
#define READ_A(MH)                                                            \
  _Pragma("unroll") for (int kk = 0; kk < 2; ++kk)                            \
  _Pragma("unroll") for (int ms = 0; ms < 4; ++ms) {                          \
    int rr = wm + (MH) * 64 + ms * 16 + l15;                                  \
    int cc = (kk * 4 + quad) ^ (rr & 7);                                      \
    af[kk][ms] = *(const bf16x8*)&Ac[rr * 64 + cc * 8];                       \
  }

#define READ_B(DST, NH)                                                       \
  _Pragma("unroll") for (int kk = 0; kk < 2; ++kk)                            \
  _Pragma("unroll") for (int ns = 0; ns < 2; ++ns) {                          \
    int rr = wn + (NH) * 32 + ns * 16 + l15;                                  \
    int cc = (kk * 4 + quad) ^ (rr & 7);                                      \
    DST[kk][ns] = *(const bf16x8*)&Bc[rr * 64 + cc * 8];                      \
  }

// 16 MFMAs for one C-quadrant (MH,NH) using held fragments.
#define MFMA_Q(MH, NH, BSET)                                                  \
  do {                                                                        \
    __builtin_amdgcn_s_setprio(1);                                            \
    _Pragma("unroll") for (int kk = 0; kk < 2; ++kk)                          \
    _Pragma("unroll") for (int ms = 0; ms < 4; ++ms)                          \
    _Pragma("unroll") for (int ns = 0; ns < 2; ++ns)                          \
      acc[(MH) * 4 + ms][(NH) * 2 + ns] =                                     \
          __builtin_amdgcn_mfma_f32_16x16x32_bf16(                            \
              af[kk][ms], BSET[kk][ns], acc[(MH) * 4 + ms][(NH) * 2 + ns],    \
              0, 0, 0);                                                       \
    __builtin_amdgcn_s_setprio(0);                                            \
  } while (0)

#define WAITV4 asm volatile("s_waitcnt vmcnt(4)" ::: "memory")
#define WAITV0 asm volatile("s_waitcnt vmcnt(0)" ::: "memory")
#define SBAR __builtin_amdgcn_s_barrier()

// ---------------- C = A * Bt^T  (both bf16 row-major, K-major rows) ----------------
// 256x256 tile, BK=64, 8 waves (2M x 4N, 128x64 each), 128KiB dbuf LDS.
// EPI: 4 = fused QKV (sel=blockIdx.y>>2): Q (x+b)/32, K x+b, V -> Vt[b][d][k]
//      2 = P = exp(S) masked, bf16; atomic row sums -> lsum
//      3 = O = (P*V) * 1/lvec[row], f32
template <int EPI>
__global__ __launch_bounds__(512, 2) void k_gemm(
    const unsigned short* __restrict__ A, const unsigned short* __restrict__ Bt,
    void* __restrict__ Cv,
    const float* __restrict__ bias_q, const float* __restrict__ bias_k,
    const float* __restrict__ bias_v,
    const float* __restrict__ lvec, float* __restrict__ lsum,
    const int* __restrict__ mask,
    long aZ, long bZ, int ldA, int ldB, int kIters)
{
  __shared__ __attribute__((aligned(16))) unsigned short As[2][256 * 64];
  __shared__ __attribute__((aligned(16))) unsigned short Bs[2][256 * 64];
  const int tid = threadIdx.x, w = tid >> 6, l = tid & 63;
  const int quad = l >> 4, l15 = l & 15;
  const int wr = w & 1, wc = w >> 1;           // 2M x 4N wave grid
  const int wm = wr * 128, wn = wc * 64;
  const int m0 = blockIdx.x * 256;
  const int z = blockIdx.z;

  int n0, sel = 0;
  if constexpr (EPI == 4) { sel = blockIdx.y >> 2; n0 = (blockIdx.y & 3) * 256; }
  else n0 = blockIdx.y * 256;

  const unsigned short* Az = A + (size_t)z * aZ;
  const unsigned short* Bz = (EPI == 4) ? (Bt + ((size_t)sel << 20))
                                        : (Bt + (size_t)z * bZ);

  floatx4 acc[8][4];
#pragma unroll
  for (int i = 0; i < 8; ++i)
#pragma unroll
    for (int j = 0; j < 4; ++j) { floatx4 zz = {0.f, 0.f, 0.f, 0.f}; acc[i][j] = zz; }

  // -------- prologue: tile0 full + AH0/BH0(1); tile0 guaranteed landed --------
  stage_half<false>(Az, As[0], m0, ldA, 0, 0, w, l);   // AH0(0)
  stage_half<true >(Bz, Bs[0], n0, ldB, 0, 0, w, l);   // BH0(0)
  stage_half<false>(Az, As[0], m0, ldA, 0, 1, w, l);   // AH1(0)
  stage_half<true >(Bz, Bs[0], n0, ldB, 0, 1, w, l);   // BH1(0)
  if (kIters > 1) {
    stage_half<false>(Az, As[1], m0, ldA, 1, 0, w, l); // AH0(1)
    stage_half<true >(Bz, Bs[1], n0, ldB, 1, 0, w, l); // BH0(1)
    WAITV4;
  } else {
    WAITV0;
  }
  SBAR;

  // -------- main loop: 4 phases/K-tile, reg-held frags, vmcnt(4)@p4 only ----
#pragma unroll 2
  for (int kt = 0; kt < kIters; ++kt) {
    const int bc = kt & 1, bn = bc ^ 1;
    const unsigned short* Ac = As[bc];
    const unsigned short* Bc = Bs[bc];
    bf16x8 af[2][4], bfr0[2][2], bfr1[2][2];

    // ---- p1: Q(0,0).  reads AH0+BH0 (12); stage AH1(t+1) -> bn ----
    READ_A(0); READ_B(bfr0, 0);
    if (kt + 1 < kIters) stage_half<false>(Az, As[bn], m0, ldA, kt + 1, 1, w, l);
    SBAR;
    MFMA_Q(0, 0, bfr0);
    SBAR;
    // ---- p2: Q(0,1).  reads BH1 (4, af held); stage BH1(t+1) -> bn ----
    READ_B(bfr1, 1);
    if (kt + 1 < kIters) stage_half<true >(Bz, Bs[bn], n0, ldB, kt + 1, 1, w, l);
    SBAR;
    MFMA_Q(0, 1, bfr1);
    SBAR;
    // ---- p3: Q(1,1).  reads AH1 (8, bfr1 held); stage AH0(t+2) -> bc ----
    READ_A(1);
    if (kt + 2 < kIters) stage_half<false>(Az, As[bc], m0, ldA, kt + 2, 0, w, l);
    SBAR;
    MFMA_Q(1, 1, bfr1);
    SBAR;
    // ---- p4: Q(1,0).  NO reads (af, bfr0 held); stage BH0(t+2) -> bc ----
    if (kt + 2 < kIters) stage_half<true >(Bz, Bs[bc], n0, ldB, kt + 2, 0, w, l);
    SBAR;
    MFMA_Q(1, 0, bfr0);
    if (kt + 2 < kIters) { WAITV4; } else { WAITV0; }
    SBAR;
  }

  // epilogue: C/D layout col = lane&15, row = quad*4 + reg  [m89/m91]
  if constexpr (EPI == 4) {
    unsigned short* C = (unsigned short*)Cv + ((size_t)sel << 24);
    const float* bs = sel == 0 ? bias_q : (sel == 1 ? bias_k : bias_v);
    if (sel < 2) {
      float sc = sel == 0 ? 0.03125f : 1.0f;
#pragma unroll
      for (int ns = 0; ns < 4; ++ns) {
        int n_g = n0 + wn + ns * 16 + l15;
        float bv = bs[n_g];
#pragma unroll
        for (int ms = 0; ms < 8; ++ms) {
          int mb = m0 + wm + ms * 16 + quad * 4;
#pragma unroll
          for (int r = 0; r < 4; ++r)
            C[(size_t)(mb + r) * 1024 + n_g] = f2bf((acc[ms][ns][r] + bv) * sc);
        }
      }
    } else {
      // V -> Vt[b][d][k]: the 4 r-values are CONSECUTIVE in k -> pack 8B stores
#pragma unroll
      for (int ns = 0; ns < 4; ++ns) {
        int n_g = n0 + wn + ns * 16 + l15;
        float bv = bs[n_g];
#pragma unroll
        for (int ms = 0; ms < 8; ++ms) {
          int m_g = m0 + wm + ms * 16 + quad * 4;   // r=0 element
          int bb = m_g >> 11, key = m_g & 2047;
          ushort4 pk;
          pk.x = f2bf(acc[ms][ns][0] + bv);
          pk.y = f2bf(acc[ms][ns][1] + bv);
          pk.z = f2bf(acc[ms][ns][2] + bv);
          pk.w = f2bf(acc[ms][ns][3] + bv);
          *(ushort4*)&C[((size_t)bb << 21) + ((size_t)n_g << 11) + key] = pk;
        }
      }
    }
  } else if constexpr (EPI == 2) {
    // P = exp(S) (max-free: |S| <= ~6), masked; atomic rowsums
    unsigned short* C = (unsigned short*)Cv + (size_t)z * 4194304;
    const int* mz = mask + z * 2048;
    float rowsum[8][4];
#pragma unroll
    for (int ms = 0; ms < 8; ++ms)
#pragma unroll
      for (int r = 0; r < 4; ++r) rowsum[ms][r] = 0.f;
#pragma unroll
    for (int ns = 0; ns < 4; ++ns) {
      int n_g = n0 + wn + ns * 16 + l15;
      int mv = mz[n_g];
#pragma unroll
      for (int ms = 0; ms < 8; ++ms) {
#pragma unroll
        for (int r = 0; r < 4; ++r) {
          int m_g = m0 + wm + ms * 16 + quad * 4 + r;
          float e = mv ? __expf(acc[ms][ns][r]) : 0.f;
          unsigned short pb = f2bf(e);
          C[(size_t)m_g * 2048 + n_g] = pb;
          rowsum[ms][r] += bf2f(pb);
        }
      }
    }
#pragma unroll
    for (int ms = 0; ms < 8; ++ms) {
#pragma unroll
      for (int r = 0; r < 4; ++r) {
        float s = rowsum[ms][r];
#pragma unroll
        for (int off = 1; off < 16; off <<= 1) s += __shfl_xor(s, off);
        if (l15 == 0) {
          int m_g = m0 + wm + ms * 16 + quad * 4 + r;
          atomicAdd(&lsum[z * 2048 + m_g], s);
        }
      }
    }
  } else {  // EPI == 3: O = (P*V)/l
    float* C = (float*)Cv + (size_t)z * 2048 * 1024;
    const float* lz = lvec + z * 2048;
#pragma unroll
    for (int ms = 0; ms < 8; ++ms) {
#pragma unroll
      for (int r = 0; r < 4; ++r) {
        int m_g = m0 + wm + ms * 16 + quad * 4 + r;
        float lw = lz[m_g];
        float inv = lw > 0.f ? 1.f / lw : 0.f;
#pragma unroll
        for (int ns = 0; ns < 4; ++ns) {
          int n_g = n0 + wn + ns * 16 + l15;
          C[(size_t)m_g * 1024 + n_g] = acc[ms][ns][r] * inv;
        }
      }
    }
  }
}

extern "C" void kernel_launch(void* const* d_in, const int* in_sizes, int n_in,
                              void* d_out, int out_size, void* d_ws, size_t ws_size,
                              hipStream_t stream) {
  const float* X    = (const float*)d_in[0];
  const int*   mask = (const int*)d_in[1];
  const float* Wq   = (const float*)d_in[2];
  const float* bq   = (const float*)d_in[3];
  const float* Wk   = (const float*)d_in[4];
  const float* bk   = (const float*)d_in[5];
  const float* Wv   = (const float*)d_in[6];
  const float* bv   = (const float*)d_in[7];
  float* out = (float*)d_out;

  constexpr size_t SZ = (size_t)16384 * 1024;
  unsigned short* Q    = (unsigned short*)d_ws;      // Q|K|Vt contiguous (sel<<24)
  float*          lvec = (float*)(Q + 3 * SZ);
  unsigned short* P    = (unsigned short*)(lvec + 16384);
  unsigned short* Xb   = P;               // overlaid: dead before P written
  unsigned short* Wt   = Xb + SZ;         // 3 x [1024][1024] bf16
  unsigned short* Vt   = Q + 2 * SZ;

  // 1. prep: X->bf16, W->Wt (bf16, transposed), lvec=0
  k_prep<<<dim3(17153), 256, 0, stream>>>(X, Xb, Wq, Wk, Wv, Wt, lvec);

  // 2. fused QKV projection (12 n-strips: 4 Q, 4 K, 4 V)
  k_gemm<4><<<dim3(64, 12, 1), 512, 0, stream>>>(
      Xb, Wt, (void*)Q, bq, bk, bv, nullptr, nullptr, nullptr,
      0, 0, 1024, 1024, 16);

  // 3. P = exp(Q K^T) masked + atomic row sums
  k_gemm<2><<<dim3(8, 8, 8), 512, 0, stream>>>(
      Q, Q + SZ, (void*)P, nullptr, nullptr, nullptr, nullptr, lvec, mask,
      2048 * 1024, 2048 * 1024, 1024, 1024, 16);

  // 4. O = (P V) / l  -> fp32 out
  k_gemm<3><<<dim3(8, 4, 8), 512, 0, stream>>>(
      P, Vt, (void*)out, nullptr, nullptr, nullptr, lvec, nullptr, nullptr,
      2048 * 2048, 1024 * 2048, 2048, 2048, 32);
}